// Round 6
// baseline (378.673 us; speedup 1.0000x reference)
//
#include <hip/hip_runtime.h>

typedef unsigned int u32;
typedef unsigned short u16;
typedef short s16x8 __attribute__((ext_vector_type(8)));
typedef float f32x4 __attribute__((ext_vector_type(4)));

#define BETA_MIN 0.1f
#define BETA_MAX 20.0f

#define MFMA16(a, b, c) __builtin_amdgcn_mfma_f32_16x16x32_bf16(a, b, c, 0, 0, 0)

__device__ __forceinline__ u16 f2bf(float f) {
    u32 u = __float_as_uint(f);
    u32 r = u + 0x7FFFu + ((u >> 16) & 1u);   // RNE on bf16 boundary
    return (u16)(r >> 16);
}
__device__ __forceinline__ float bf2f(u16 h) {
    return __uint_as_float(((u32)h) << 16);
}
__device__ __forceinline__ f32x4 zero4() {
    f32x4 z = {0.f, 0.f, 0.f, 0.f};
    return z;
}

// async global->LDS 16B; lds dest wave-uniform (HW adds lane*16)
__device__ __forceinline__ void cp16(const u16* g, u16* l) {
    __builtin_amdgcn_global_load_lds(
        (const __attribute__((address_space(1))) u32*)g,
        (__attribute__((address_space(3))) u32*)l, 16, 0, 0);
}

// DPP cross-lane within 16-lane rows (VALU latency, off the LDS pipe)
template <int CTRL>
__device__ __forceinline__ float dppf(float x) {
    return __int_as_float(__builtin_amdgcn_update_dpp(
        0, __float_as_int(x), CTRL, 0xF, 0xF, false));
}
__device__ __forceinline__ float rowmax16(float x) {
    x = fmaxf(x, dppf<0xB1>(x));    // quad_perm xor1
    x = fmaxf(x, dppf<0x4E>(x));    // quad_perm xor2
    x = fmaxf(x, dppf<0x124>(x));   // row_ror:4
    x = fmaxf(x, dppf<0x128>(x));   // row_ror:8
    return x;
}
__device__ __forceinline__ float rowsum16(float x) {
    x += dppf<0xB1>(x);
    x += dppf<0x4E>(x);
    x += dppf<0x124>(x);
    x += dppf<0x128>(x);
    return x;
}

// ---------------------------------------------------------------- prep kernels
// P1: conv_hilo(x) for all blocks + rows_kernel folded into low blocks.
__global__ void prep_x_kernel(const float* __restrict__ x, const float* __restrict__ t,
                              u16* __restrict__ Qhi, u16* __restrict__ Qlo,
                              float* __restrict__ rowc, int N) {
    int idx = blockIdx.x * 256 + threadIdx.x;
    int total4 = N * 32;                       // N*128/4 float4 chunks
    if (idx < total4) {
        float4 v = ((const float4*)x)[idx];
        float f[4] = {v.x, v.y, v.z, v.w};
        u16 h[4], l[4];
#pragma unroll
        for (int j = 0; j < 4; ++j) {
            h[j] = f2bf(f[j]);
            l[j] = f2bf(f[j] - bf2f(h[j]));
        }
        ((uint2*)Qhi)[idx] = make_uint2((u32)h[0] | ((u32)h[1] << 16), (u32)h[2] | ((u32)h[3] << 16));
        ((uint2*)Qlo)[idx] = make_uint2((u32)l[0] | ((u32)l[1] << 16), (u32)l[2] | ((u32)l[3] << 16));
    }
    if (idx < N) {
        float tv   = t[idx];
        float lm   = -0.25f * tv * tv * (BETA_MAX - BETA_MIN) - 0.5f * tv * BETA_MIN;
        float mean = __expf(lm);
        float e2   = __expf(2.0f * lm);
        float s2   = fmaxf(1.0f - e2, 1e-12f);
        float iv   = 1.0f / s2;
        rowc[idx * 4 + 0] = mean * iv;
        rowc[idx * 4 + 1] = -0.5f * mean * mean * iv;
        rowc[idx * 4 + 2] = iv;
        rowc[idx * 4 + 3] = 0.f;
    }
}

// P2: 64 train rows per block, single pass over the 16 MB train array.
// Khi/Klo/y2 coalesced; Vt transposed through LDS so stores are 16B-coalesced.
__global__ void prep_train_kernel(const float* __restrict__ train, u16* __restrict__ Khi,
                                  u16* __restrict__ Klo, u16* __restrict__ Vt,
                                  float* __restrict__ y2, int M) {
    __shared__ u16 sT[128][72];    // [d][mm]; stride 72 u16 = 144B, 16B-aligned rows
    int wave = threadIdx.x >> 6, lane = threadIdx.x & 63;
    int m0 = blockIdx.x * 64;
#pragma unroll 4
    for (int r = 0; r < 16; ++r) {
        int mm = wave * 16 + r;
        int m  = m0 + mm;
        float2 v = *(const float2*)(train + (size_t)m * 128 + lane * 2);
        u16 h0 = f2bf(v.x), l0 = f2bf(v.x - bf2f(h0));
        u16 h1 = f2bf(v.y), l1 = f2bf(v.y - bf2f(h1));
        ((u32*)Khi)[(size_t)m * 64 + lane] = (u32)h0 | ((u32)h1 << 16);
        ((u32*)Klo)[(size_t)m * 64 + lane] = (u32)l0 | ((u32)l1 << 16);
        sT[lane * 2 + 0][mm] = h0;
        sT[lane * 2 + 1][mm] = h1;
        float s = v.x * v.x + v.y * v.y;
#pragma unroll
        for (int d = 1; d < 64; d <<= 1) s += __shfl_xor(s, d);
        if (lane == 0) y2[m] = s;
    }
    __syncthreads();
    // writeback: 128 d-rows x 64 m x 2B, 16B chunks coalesced along m
#pragma unroll
    for (int c = threadIdx.x; c < 1024; c += 256) {
        int d = c >> 3, j = c & 7;
        *(uint4*)(Vt + (size_t)d * M + m0 + j * 8) = *(const uint4*)&sT[d][j * 8];
    }
}

// ---------------------------------------------------------------- flash kernel
// R4-proven structure, resized for occupancy:
// grid = (split, N/64) -> 1024 blocks = exactly 4/CU (XCD = chunk%8 affinity).
// block = 256 (4 waves, 16 q-rows/wave); K-tile = 32; LDS 37,888B -> 4 blk/CU;
// __launch_bounds__(256,4) -> <=128 VGPR -> 16 waves/CU (R4 had 8, 60% stall).
// S = a*(Qh*Kh + Ql*Kh + Qh*Kl) + b*y2   (bf16x3)
// K hi/lo: double-buffered LDS via global_load_lds, XOR-swizzled chunks;
// one waitcnt+barrier per iter, drain lands AFTER compute. V/y2 from global.
__device__ __forceinline__ s16x8 skf(const u16* buf, int h, int kb, int l15, int quad) {
    return *(const s16x8*)(buf + (((h * 16 + l15) * 16 + (((kb * 4) + quad) ^ l15)) * 8));
}

__global__ __launch_bounds__(256, 4)
void flash_kernel(const u16* __restrict__ Khi, const u16* __restrict__ Klo,
                  const u16* __restrict__ Vt,  const u16* __restrict__ Qhi,
                  const u16* __restrict__ Qlo, const float* __restrict__ rowc,
                  const float* __restrict__ y2, float* __restrict__ partO,
                  float* __restrict__ partML, int N, int M, int mchunk) {
    __shared__ __align__(16) u16 sKhi[2][32 * 128];   // 16 KB
    __shared__ __align__(16) u16 sKlo[2][32 * 128];   // 16 KB
    __shared__ __align__(16) u16 sP[4][16][40];       //  5 KB

    const int tid  = threadIdx.x;
    const int wave = tid >> 6, lane = tid & 63;
    const int l15  = lane & 15, quad = lane >> 4;
    const int chunk = blockIdx.x, qb = blockIdx.y;
    const int q0 = qb * 64 + wave * 16;
    const int m_begin = chunk * mchunk;
    const int cbase = wave * 64 + lane;

    // Q fragments (A-layout: A[m=l15][k=quad*8+j])
    s16x8 qh[4], ql[4];
    {
        int row = q0 + l15;
        const u16* ph = Qhi + (size_t)row * 128;
        const u16* pl = Qlo + (size_t)row * 128;
#pragma unroll
        for (int kb = 0; kb < 4; ++kb) {
            qh[kb] = *(const s16x8*)(ph + kb * 32 + quad * 8);
            ql[kb] = *(const s16x8*)(pl + kb * 32 + quad * 8);
        }
    }
    float av[4], bv[4];
#pragma unroll
    for (int k = 0; k < 4; ++k) {
        int r = q0 + quad * 4 + k;
        av[k] = rowc[r * 4 + 0];
        bv[k] = rowc[r * 4 + 1];
    }

    f32x4 O[8];
#pragma unroll
    for (int db = 0; db < 8; ++db) O[db] = zero4();
    float m_run[4], l_run[4];
#pragma unroll
    for (int k = 0; k < 4; ++k) { m_run[k] = -INFINITY; l_run[k] = 0.f; }

    // stage K-tile m0 into dbuf half b: 512 swizzled 16B chunks each for hi/lo
    auto stage = [&](int m0, int b) {
#pragma unroll
        for (int r = 0; r < 2; ++r) {
            int c = r * 256 + cbase;
            int row = c >> 4;
            int g = (c & 15) ^ (row & 15);
            cp16(Khi + (size_t)(m0 + row) * 128 + g * 8, &sKhi[b][(r * 256 + wave * 64) * 8]);
            cp16(Klo + (size_t)(m0 + row) * 128 + g * 8, &sKlo[b][(r * 256 + wave * 64) * 8]);
        }
    };

    // prologue: tile 0 -> buf 0
    stage(m_begin, 0);
    asm volatile("s_waitcnt vmcnt(0)" ::: "memory");
    __syncthreads();

    const int iters = mchunk / 32;
    for (int it = 0; it < iters; ++it) {
        const int m0 = m_begin + it * 32;
        const u16* bKhi = sKhi[it & 1];
        const u16* bKlo = sKlo[it & 1];

        // issue next tile's staging into the other half (overlaps this compute)
        if (it + 1 < iters) stage(m0 + 32, (it + 1) & 1);

        // V fragments + y2 for CURRENT tile (global; consumed last, in PV)
        s16x8 vb[8];
#pragma unroll
        for (int db = 0; db < 8; ++db)
            vb[db] = *(const s16x8*)(Vt + (size_t)(db * 16 + l15) * M + m0 + quad * 8);
        float y2v0 = y2[m0 + l15];
        float y2v1 = y2[m0 + 16 + l15];

        // S GEMM: bf16x3, swizzled fragment reads from current buffer
        f32x4 S[2];
        S[0] = zero4(); S[1] = zero4();
#pragma unroll
        for (int kb = 0; kb < 4; ++kb) {
            s16x8 bh0 = skf(bKhi, 0, kb, l15, quad);
            s16x8 bh1 = skf(bKhi, 1, kb, l15, quad);
            s16x8 bl0 = skf(bKlo, 0, kb, l15, quad);
            s16x8 bl1 = skf(bKlo, 1, kb, l15, quad);
            S[0] = MFMA16(qh[kb], bh0, S[0]);
            S[0] = MFMA16(ql[kb], bh0, S[0]);
            S[0] = MFMA16(qh[kb], bl0, S[0]);
            S[1] = MFMA16(qh[kb], bh1, S[1]);
            S[1] = MFMA16(ql[kb], bh1, S[1]);
            S[1] = MFMA16(qh[kb], bl1, S[1]);
        }

        // online softmax; O alpha-scale behind a wave-uniform vote
        float alph[4];
        int upd = 0;
#pragma unroll
        for (int k = 0; k < 4; ++k) {
            float s0 = av[k] * S[0][k] + bv[k] * y2v0;
            float s1 = av[k] * S[1][k] + bv[k] * y2v1;
            float rm = rowmax16(fmaxf(s0, s1));
            float mnew  = fmaxf(m_run[k], rm);
            float a_    = __expf(m_run[k] - mnew);   // ==1 when no update
            float p0 = __expf(s0 - mnew);
            float p1 = __expf(s1 - mnew);
            l_run[k] = l_run[k] * a_ + (p0 + p1);
            m_run[k] = mnew;
            alph[k]  = a_;
            upd |= (a_ < 1.0f);
            sP[wave][quad * 4 + k][l15]      = f2bf(p0);
            sP[wave][quad * 4 + k][16 + l15] = f2bf(p1);
        }
        if (__any(upd)) {
#pragma unroll
            for (int db = 0; db < 8; ++db)
#pragma unroll
                for (int k = 0; k < 4; ++k) O[db][k] *= alph[k];
        }
        // same-wave sP write->read ordering (per-wave region, DS in-order/wave)
        asm volatile("s_waitcnt lgkmcnt(0)" ::: "memory");

        s16x8 pa = *(const s16x8*)&sP[wave][l15][quad * 8];
#pragma unroll
        for (int db = 0; db < 8; ++db)
            O[db] = MFMA16(pa, vb[db], O[db]);

        // end-of-iter: drain next tile's staging, then the single barrier.
        asm volatile("s_waitcnt vmcnt(0)" ::: "memory");
        __syncthreads();
    }

    // epilogue: unnormalized O + (m, l) partials
#pragma unroll
    for (int db = 0; db < 8; ++db) {
#pragma unroll
        for (int k = 0; k < 4; ++k) {
            int row = q0 + quad * 4 + k;
            partO[((size_t)chunk * N + row) * 128 + db * 16 + l15] = O[db][k];
        }
    }
#pragma unroll
    for (int k = 0; k < 4; ++k) {
        float lsum = rowsum16(l_run[k]);
        if (l15 == 0) {
            int row = q0 + quad * 4 + k;
            partML[((size_t)chunk * N + row) * 2 + 0] = m_run[k];
            partML[((size_t)chunk * N + row) * 2 + 1] = lsum;
        }
    }
}

// ---------------------------------------------------------------- combine
__global__ void combine_kernel(const float* __restrict__ partO, const float* __restrict__ partML,
                               const float* __restrict__ x, const float* __restrict__ rowc,
                               float* __restrict__ out, int N, int split) {
    int n = blockIdx.x, d = threadIdx.x;
    float Mx = -INFINITY;
    for (int c = 0; c < split; ++c)
        Mx = fmaxf(Mx, partML[((size_t)c * N + n) * 2]);
    float L = 0.f, acc = 0.f;
    for (int c = 0; c < split; ++c) {
        float w = __expf(partML[((size_t)c * N + n) * 2] - Mx);
        L   += w * partML[((size_t)c * N + n) * 2 + 1];
        acc += w * partO[((size_t)c * N + n) * 128 + d];
    }
    float evals = acc / L;
    if (evals != evals) evals = 0.f;   // reference's isnan guard
    float iv = rowc[n * 4 + 2];
    out[(size_t)n * 128 + d] = (evals - x[(size_t)n * 128 + d]) * iv;
}

// ---------------------------------------------------------------- launch
extern "C" void kernel_launch(void* const* d_in, const int* in_sizes, int n_in,
                              void* d_out, int out_size, void* d_ws, size_t ws_size,
                              hipStream_t stream) {
    const float* x     = (const float*)d_in[0];
    const float* t     = (const float*)d_in[1];
    const float* train = (const float*)d_in[2];
    float* out = (float*)d_out;

    const int N = in_sizes[1];            // 4096
    const int D = 128;
    const int M = in_sizes[2] / D;        // 16384

    char* ws = (char*)d_ws;
    size_t off = 0;
    auto alloc = [&](size_t bytes) -> void* {
        void* p = ws + off;
        off = (off + bytes + 255) & ~(size_t)255;
        return p;
    };
    u16* Khi   = (u16*)alloc((size_t)M * D * 2);
    u16* Klo   = (u16*)alloc((size_t)M * D * 2);
    u16* Vt    = (u16*)alloc((size_t)M * D * 2);
    u16* Qhi   = (u16*)alloc((size_t)N * D * 2);
    u16* Qlo   = (u16*)alloc((size_t)N * D * 2);
    float* rowc = (float*)alloc((size_t)N * 16);
    float* y2   = (float*)alloc((size_t)M * 4);
    size_t base = off;
    size_t per  = (size_t)N * D * 4 + (size_t)N * 8 + 512;   // partO + partML per chunk
    int split = 16;                       // 16 x 64 = 1024 blocks = 4/CU
    while (split > 1 && base + per * split > ws_size) split >>= 1;
    float* partO  = (float*)alloc((size_t)split * N * D * 4);
    float* partML = (float*)alloc((size_t)split * N * 8);

    prep_x_kernel<<<(N * 32 + 255) / 256, 256, 0, stream>>>(x, t, Qhi, Qlo, rowc, N);
    prep_train_kernel<<<M / 64, 256, 0, stream>>>(train, Khi, Klo, Vt, y2, M);

    int mchunk = M / split;
    dim3 grid(split, N / 64);             // chunk-major: XCD = chunk % 8 (L2 affinity)
    flash_kernel<<<grid, 256, 0, stream>>>(Khi, Klo, Vt, Qhi, Qlo, rowc, y2,
                                           partO, partML, N, M, mchunk);
    combine_kernel<<<N, 128, 0, stream>>>(partO, partML, x, rowc, out, N, split);
}

// Round 7
// 376.280 us; speedup vs baseline: 1.0064x; 1.0064x over previous
//
#include <hip/hip_runtime.h>

typedef unsigned int u32;
typedef unsigned short u16;
typedef short s16x8 __attribute__((ext_vector_type(8)));
typedef float f32x4 __attribute__((ext_vector_type(4)));

#define BETA_MIN 0.1f
#define BETA_MAX 20.0f

#define MFMA16(a, b, c) __builtin_amdgcn_mfma_f32_16x16x32_bf16(a, b, c, 0, 0, 0)

__device__ __forceinline__ u16 f2bf(float f) {
    u32 u = __float_as_uint(f);
    u32 r = u + 0x7FFFu + ((u >> 16) & 1u);   // RNE on bf16 boundary
    return (u16)(r >> 16);
}
__device__ __forceinline__ float bf2f(u16 h) {
    return __uint_as_float(((u32)h) << 16);
}
__device__ __forceinline__ f32x4 zero4() {
    f32x4 z = {0.f, 0.f, 0.f, 0.f};
    return z;
}

// async global->LDS 16B; lds dest wave-uniform (HW adds lane*16)
__device__ __forceinline__ void cp16(const u16* g, u16* l) {
    __builtin_amdgcn_global_load_lds(
        (const __attribute__((address_space(1))) u32*)g,
        (__attribute__((address_space(3))) u32*)l, 16, 0, 0);
}

// DPP cross-lane within 16-lane rows (VALU latency, off the LDS pipe)
template <int CTRL>
__device__ __forceinline__ float dppf(float x) {
    return __int_as_float(__builtin_amdgcn_update_dpp(
        0, __float_as_int(x), CTRL, 0xF, 0xF, false));
}
__device__ __forceinline__ float rowmax16(float x) {
    x = fmaxf(x, dppf<0xB1>(x));    // quad_perm xor1
    x = fmaxf(x, dppf<0x4E>(x));    // quad_perm xor2
    x = fmaxf(x, dppf<0x124>(x));   // row_ror:4
    x = fmaxf(x, dppf<0x128>(x));   // row_ror:8
    return x;
}
__device__ __forceinline__ float rowsum16(float x) {
    x += dppf<0xB1>(x);
    x += dppf<0x4E>(x);
    x += dppf<0x124>(x);
    x += dppf<0x128>(x);
    return x;
}

// ---------------------------------------------------------------- prep kernels
// P1: conv_hilo(x) for all blocks + rows_kernel folded into low blocks.
__global__ void prep_x_kernel(const float* __restrict__ x, const float* __restrict__ t,
                              u16* __restrict__ Qhi, u16* __restrict__ Qlo,
                              float* __restrict__ rowc, int N) {
    int idx = blockIdx.x * 256 + threadIdx.x;
    int total4 = N * 32;                       // N*128/4 float4 chunks
    if (idx < total4) {
        float4 v = ((const float4*)x)[idx];
        float f[4] = {v.x, v.y, v.z, v.w};
        u16 h[4], l[4];
#pragma unroll
        for (int j = 0; j < 4; ++j) {
            h[j] = f2bf(f[j]);
            l[j] = f2bf(f[j] - bf2f(h[j]));
        }
        ((uint2*)Qhi)[idx] = make_uint2((u32)h[0] | ((u32)h[1] << 16), (u32)h[2] | ((u32)h[3] << 16));
        ((uint2*)Qlo)[idx] = make_uint2((u32)l[0] | ((u32)l[1] << 16), (u32)l[2] | ((u32)l[3] << 16));
    }
    if (idx < N) {
        float tv   = t[idx];
        float lm   = -0.25f * tv * tv * (BETA_MAX - BETA_MIN) - 0.5f * tv * BETA_MIN;
        float mean = __expf(lm);
        float e2   = __expf(2.0f * lm);
        float s2   = fmaxf(1.0f - e2, 1e-12f);
        float iv   = 1.0f / s2;
        rowc[idx * 4 + 0] = mean * iv;
        rowc[idx * 4 + 1] = -0.5f * mean * mean * iv;
        rowc[idx * 4 + 2] = iv;
        rowc[idx * 4 + 3] = 0.f;
    }
}

// P2: 64 train rows per block, single pass over the 16 MB train array.
// Khi/Klo/y2 coalesced; Vt transposed through LDS so stores are 16B-coalesced.
__global__ void prep_train_kernel(const float* __restrict__ train, u16* __restrict__ Khi,
                                  u16* __restrict__ Klo, u16* __restrict__ Vt,
                                  float* __restrict__ y2, int M) {
    __shared__ u16 sT[128][72];    // [d][mm]; stride 72 u16 = 144B, 16B-aligned rows
    int wave = threadIdx.x >> 6, lane = threadIdx.x & 63;
    int m0 = blockIdx.x * 64;
#pragma unroll 4
    for (int r = 0; r < 16; ++r) {
        int mm = wave * 16 + r;
        int m  = m0 + mm;
        float2 v = *(const float2*)(train + (size_t)m * 128 + lane * 2);
        u16 h0 = f2bf(v.x), l0 = f2bf(v.x - bf2f(h0));
        u16 h1 = f2bf(v.y), l1 = f2bf(v.y - bf2f(h1));
        ((u32*)Khi)[(size_t)m * 64 + lane] = (u32)h0 | ((u32)h1 << 16);
        ((u32*)Klo)[(size_t)m * 64 + lane] = (u32)l0 | ((u32)l1 << 16);
        sT[lane * 2 + 0][mm] = h0;
        sT[lane * 2 + 1][mm] = h1;
        float s = v.x * v.x + v.y * v.y;
#pragma unroll
        for (int d = 1; d < 64; d <<= 1) s += __shfl_xor(s, d);
        if (lane == 0) y2[m] = s;
    }
    __syncthreads();
    // writeback: 128 d-rows x 64 m x 2B, 16B chunks coalesced along m
#pragma unroll
    for (int c = threadIdx.x; c < 1024; c += 256) {
        int d = c >> 3, j = c & 7;
        *(uint4*)(Vt + (size_t)d * M + m0 + j * 8) = *(const uint4*)&sT[d][j * 8];
    }
}

// ---------------------------------------------------------------- flash kernel
// grid = (N/64, split) with qb = blockIdx.x INNER: a contiguous 128-block
// linear range (one XCD's fill under contiguous dispatch) spans only ~2
// chunks -> per-XCD L2 working set ~1.5MB K/V + 2MB Q stream < 4MB.
// [R6 post-mortem: chunk-inner ordering gave every XCD all 16 chunks ->
//  16MB >> L2 -> FETCH_SIZE 638MB, flash fetch-bound at 305us.]
// block = 256 (4 waves, 16 q-rows/wave); K-tile = 32; LDS 37,888B -> 4 blk/CU;
// __launch_bounds__(256,4) -> <=128 VGPR -> 16 waves/CU.
// S = a*(Qh*Kh + Ql*Kh + Qh*Kl) + b*y2   (bf16x3)
// K hi/lo: double-buffered LDS via global_load_lds, XOR-swizzled chunks;
// one waitcnt+barrier per iter, drain lands AFTER compute. V/y2 from global.
__device__ __forceinline__ s16x8 skf(const u16* buf, int h, int kb, int l15, int quad) {
    return *(const s16x8*)(buf + (((h * 16 + l15) * 16 + (((kb * 4) + quad) ^ l15)) * 8));
}

__global__ __launch_bounds__(256, 4)
void flash_kernel(const u16* __restrict__ Khi, const u16* __restrict__ Klo,
                  const u16* __restrict__ Vt,  const u16* __restrict__ Qhi,
                  const u16* __restrict__ Qlo, const float* __restrict__ rowc,
                  const float* __restrict__ y2, float* __restrict__ partO,
                  float* __restrict__ partML, int N, int M, int mchunk) {
    __shared__ __align__(16) u16 sKhi[2][32 * 128];   // 16 KB
    __shared__ __align__(16) u16 sKlo[2][32 * 128];   // 16 KB
    __shared__ __align__(16) u16 sP[4][16][40];       //  5 KB

    const int tid  = threadIdx.x;
    const int wave = tid >> 6, lane = tid & 63;
    const int l15  = lane & 15, quad = lane >> 4;
    const int qb = blockIdx.x, chunk = blockIdx.y;
    const int q0 = qb * 64 + wave * 16;
    const int m_begin = chunk * mchunk;
    const int cbase = wave * 64 + lane;

    // Q fragments (A-layout: A[m=l15][k=quad*8+j])
    s16x8 qh[4], ql[4];
    {
        int row = q0 + l15;
        const u16* ph = Qhi + (size_t)row * 128;
        const u16* pl = Qlo + (size_t)row * 128;
#pragma unroll
        for (int kb = 0; kb < 4; ++kb) {
            qh[kb] = *(const s16x8*)(ph + kb * 32 + quad * 8);
            ql[kb] = *(const s16x8*)(pl + kb * 32 + quad * 8);
        }
    }
    float av[4], bv[4];
#pragma unroll
    for (int k = 0; k < 4; ++k) {
        int r = q0 + quad * 4 + k;
        av[k] = rowc[r * 4 + 0];
        bv[k] = rowc[r * 4 + 1];
    }

    f32x4 O[8];
#pragma unroll
    for (int db = 0; db < 8; ++db) O[db] = zero4();
    float m_run[4], l_run[4];
#pragma unroll
    for (int k = 0; k < 4; ++k) { m_run[k] = -INFINITY; l_run[k] = 0.f; }

    // stage K-tile m0 into dbuf half b: 512 swizzled 16B chunks each for hi/lo
    auto stage = [&](int m0, int b) {
#pragma unroll
        for (int r = 0; r < 2; ++r) {
            int c = r * 256 + cbase;
            int row = c >> 4;
            int g = (c & 15) ^ (row & 15);
            cp16(Khi + (size_t)(m0 + row) * 128 + g * 8, &sKhi[b][(r * 256 + wave * 64) * 8]);
            cp16(Klo + (size_t)(m0 + row) * 128 + g * 8, &sKlo[b][(r * 256 + wave * 64) * 8]);
        }
    };

    // prologue: tile 0 -> buf 0
    stage(m_begin, 0);
    asm volatile("s_waitcnt vmcnt(0)" ::: "memory");
    __syncthreads();

    const int iters = mchunk / 32;
    for (int it = 0; it < iters; ++it) {
        const int m0 = m_begin + it * 32;
        const u16* bKhi = sKhi[it & 1];
        const u16* bKlo = sKlo[it & 1];

        // issue next tile's staging into the other half (overlaps this compute)
        if (it + 1 < iters) stage(m0 + 32, (it + 1) & 1);

        // V fragments + y2 for CURRENT tile (global; consumed last, in PV)
        s16x8 vb[8];
#pragma unroll
        for (int db = 0; db < 8; ++db)
            vb[db] = *(const s16x8*)(Vt + (size_t)(db * 16 + l15) * M + m0 + quad * 8);
        float y2v0 = y2[m0 + l15];
        float y2v1 = y2[m0 + 16 + l15];

        // S GEMM: bf16x3, swizzled fragment reads from current buffer
        f32x4 S[2];
        S[0] = zero4(); S[1] = zero4();
#pragma unroll
        for (int kb = 0; kb < 4; ++kb) {
            s16x8 bh0 = skf(bKhi, 0, kb, l15, quad);
            s16x8 bh1 = skf(bKhi, 1, kb, l15, quad);
            s16x8 bl0 = skf(bKlo, 0, kb, l15, quad);
            s16x8 bl1 = skf(bKlo, 1, kb, l15, quad);
            S[0] = MFMA16(qh[kb], bh0, S[0]);
            S[0] = MFMA16(ql[kb], bh0, S[0]);
            S[0] = MFMA16(qh[kb], bl0, S[0]);
            S[1] = MFMA16(qh[kb], bh1, S[1]);
            S[1] = MFMA16(ql[kb], bh1, S[1]);
            S[1] = MFMA16(qh[kb], bl1, S[1]);
        }

        // online softmax; O alpha-scale behind a wave-uniform vote
        float alph[4];
        int upd = 0;
#pragma unroll
        for (int k = 0; k < 4; ++k) {
            float s0 = av[k] * S[0][k] + bv[k] * y2v0;
            float s1 = av[k] * S[1][k] + bv[k] * y2v1;
            float rm = rowmax16(fmaxf(s0, s1));
            float mnew  = fmaxf(m_run[k], rm);
            float a_    = __expf(m_run[k] - mnew);   // ==1 when no update
            float p0 = __expf(s0 - mnew);
            float p1 = __expf(s1 - mnew);
            l_run[k] = l_run[k] * a_ + (p0 + p1);
            m_run[k] = mnew;
            alph[k]  = a_;
            upd |= (a_ < 1.0f);
            sP[wave][quad * 4 + k][l15]      = f2bf(p0);
            sP[wave][quad * 4 + k][16 + l15] = f2bf(p1);
        }
        if (__any(upd)) {
#pragma unroll
            for (int db = 0; db < 8; ++db)
#pragma unroll
                for (int k = 0; k < 4; ++k) O[db][k] *= alph[k];
        }
        // same-wave sP write->read ordering (per-wave region, DS in-order/wave)
        asm volatile("s_waitcnt lgkmcnt(0)" ::: "memory");

        s16x8 pa = *(const s16x8*)&sP[wave][l15][quad * 8];
#pragma unroll
        for (int db = 0; db < 8; ++db)
            O[db] = MFMA16(pa, vb[db], O[db]);

        // end-of-iter: drain next tile's staging, then the single barrier.
        asm volatile("s_waitcnt vmcnt(0)" ::: "memory");
        __syncthreads();
    }

    // epilogue: unnormalized O + (m, l) partials
#pragma unroll
    for (int db = 0; db < 8; ++db) {
#pragma unroll
        for (int k = 0; k < 4; ++k) {
            int row = q0 + quad * 4 + k;
            partO[((size_t)chunk * N + row) * 128 + db * 16 + l15] = O[db][k];
        }
    }
#pragma unroll
    for (int k = 0; k < 4; ++k) {
        float lsum = rowsum16(l_run[k]);
        if (l15 == 0) {
            int row = q0 + quad * 4 + k;
            partML[((size_t)chunk * N + row) * 2 + 0] = m_run[k];
            partML[((size_t)chunk * N + row) * 2 + 1] = lsum;
        }
    }
}

// ---------------------------------------------------------------- combine
__global__ void combine_kernel(const float* __restrict__ partO, const float* __restrict__ partML,
                               const float* __restrict__ x, const float* __restrict__ rowc,
                               float* __restrict__ out, int N, int split) {
    int n = blockIdx.x, d = threadIdx.x;
    float Mx = -INFINITY;
    for (int c = 0; c < split; ++c)
        Mx = fmaxf(Mx, partML[((size_t)c * N + n) * 2]);
    float L = 0.f, acc = 0.f;
    for (int c = 0; c < split; ++c) {
        float w = __expf(partML[((size_t)c * N + n) * 2] - Mx);
        L   += w * partML[((size_t)c * N + n) * 2 + 1];
        acc += w * partO[((size_t)c * N + n) * 128 + d];
    }
    float evals = acc / L;
    if (evals != evals) evals = 0.f;   // reference's isnan guard
    float iv = rowc[n * 4 + 2];
    out[(size_t)n * 128 + d] = (evals - x[(size_t)n * 128 + d]) * iv;
}

// ---------------------------------------------------------------- launch
extern "C" void kernel_launch(void* const* d_in, const int* in_sizes, int n_in,
                              void* d_out, int out_size, void* d_ws, size_t ws_size,
                              hipStream_t stream) {
    const float* x     = (const float*)d_in[0];
    const float* t     = (const float*)d_in[1];
    const float* train = (const float*)d_in[2];
    float* out = (float*)d_out;

    const int N = in_sizes[1];            // 4096
    const int D = 128;
    const int M = in_sizes[2] / D;        // 16384

    char* ws = (char*)d_ws;
    size_t off = 0;
    auto alloc = [&](size_t bytes) -> void* {
        void* p = ws + off;
        off = (off + bytes + 255) & ~(size_t)255;
        return p;
    };
    u16* Khi   = (u16*)alloc((size_t)M * D * 2);
    u16* Klo   = (u16*)alloc((size_t)M * D * 2);
    u16* Vt    = (u16*)alloc((size_t)M * D * 2);
    u16* Qhi   = (u16*)alloc((size_t)N * D * 2);
    u16* Qlo   = (u16*)alloc((size_t)N * D * 2);
    float* rowc = (float*)alloc((size_t)N * 16);
    float* y2   = (float*)alloc((size_t)M * 4);
    size_t base = off;
    size_t per  = (size_t)N * D * 4 + (size_t)N * 8 + 512;   // partO + partML per chunk
    int split = 16;                       // 64 x 16 = 1024 blocks = 4/CU
    while (split > 1 && base + per * split > ws_size) split >>= 1;
    float* partO  = (float*)alloc((size_t)split * N * D * 4);
    float* partML = (float*)alloc((size_t)split * N * 8);

    prep_x_kernel<<<(N * 32 + 255) / 256, 256, 0, stream>>>(x, t, Qhi, Qlo, rowc, N);
    prep_train_kernel<<<M / 64, 256, 0, stream>>>(train, Khi, Klo, Vt, y2, M);

    int mchunk = M / split;
    dim3 grid(N / 64, split);             // qb INNER: contiguous XCD fill shares a chunk
    flash_kernel<<<grid, 256, 0, stream>>>(Khi, Klo, Vt, Qhi, Qlo, rowc, y2,
                                           partO, partML, N, M, mchunk);
    combine_kernel<<<N, 128, 0, stream>>>(partO, partML, x, rowc, out, N, split);
}